// Round 5
// baseline (587.630 us; speedup 1.0000x reference)
//
#include <hip/hip_runtime.h>
#include <hip/hip_bf16.h>

#define HH 352
#define WW 1216
#define HWSZ (HH * WW)   // 428032
#define TT 6

// ---------------- workspace layout (in floats) ----------------
// [0]            : int mode flag (1 = bf16 inputs, 0 = fp32 inputs)
// [16 ..)        : repacked conv weights, per t: 25 bias + 25*72 weights (stride 1825)
// [11008 ..)     : tail weights
// [12032 ..)     : FB 7 planes (t=0..5 outputs, idx 6 = converted feat_init)
// then           : AGG 2 planes
#define WS_CW   16
#define WS_TW   11008
#define WS_FB   12032

typedef __attribute__((ext_vector_type(4))) float f32x4;
typedef __attribute__((ext_vector_type(8))) short s16x8;
union FU { unsigned int u[4]; s16x8 v; };

__device__ inline float ld_in(const void* p, long long i, int bf) {
    return bf ? __bfloat162float(((const __hip_bfloat16*)p)[i]) : ((const float*)p)[i];
}

// split v into bf16 hi (low16) + bf16 lo (high16), RNE
__device__ inline unsigned int bfsplit_pack(float v) {
    unsigned int uv = __float_as_uint(v);
    unsigned int h = (uv + 0x7FFFu + ((uv >> 16) & 1u)) >> 16;
    float hf = __uint_as_float(h << 16);
    float r = v - hf;
    unsigned int ur = __float_as_uint(r);
    unsigned int l = (ur + 0x7FFFu + ((ur >> 16) & 1u)) >> 16;
    return (h & 0xFFFFu) | (l << 16);
}

__device__ inline int detect_mode(const void* guid) {
    const unsigned int* u = (const unsigned int*)guid;
    int cnt = 0;
    for (int i = 0; i < 128; ++i) {
        unsigned int lo = u[i] & 0xFFFFu;
        int e = (int)((lo >> 7) & 0xFF);
        if (e >= 110 && e <= 140) cnt++;
    }
    return (cnt >= 96) ? 1 : 0;
}

// ---------------- prep: dtype detect + weight repack + feat convert ----------------
__global__ __launch_bounds__(256) void prep_all(
        const void* feat_init, const void* guid,
        const void* aww, const void* awb, const void* aow, const void* aob,
        const void* projw, const void* bng, const void* bnb,
        const void* bnm, const void* bnv,
        const void* l0w, const void* l0b, const void* lsw, const void* lsb,
        const void* l1w, const void* l1b, const void* l2w, const void* l2b,
        const void* sqw, const void* sqb, const void* lcw, const void* lcb,
        float* ws) {
    __shared__ int smode;
    if (threadIdx.x == 0) {
        int mode = detect_mode(guid);
        smode = mode;
        if (blockIdx.x == 0) *(int*)ws = mode;
    }
    __syncthreads();
    const int bf = smode;
    // feat convert (all blocks)
    {
        int i = blockIdx.x * 256 + threadIdx.x;
        if (i < HWSZ) ws[WS_FB + 6 * HWSZ + i] = ld_in(feat_init, i, bf);
    }
    if (blockIdx.x >= 32) return;
    const int tid = blockIdx.x * 256 + threadIdx.x;
    const int stp = 32 * 256;
    float* cw = ws + WS_CW;
    // aff weights (T,9,8,3,3) -> cw[t*1825 + 25 + co*72 + ci*9 + tap]
    for (int idx = tid; idx < TT * 9 * 72; idx += stp) {
        int t = idx / 648; int r = idx % 648;
        int co = r / 72; int ci = (r % 72) / 9; int tap = r % 9;
        cw[t * 1825 + 25 + co * 72 + ci * 9 + tap] = ld_in(aww, idx, bf);
    }
    // off weights (T,16,8,3,3) -> co' = 9+co
    for (int idx = tid; idx < TT * 16 * 72; idx += stp) {
        int t = idx / 1152; int r = idx % 1152;
        int co = r / 72; int ci = (r % 72) / 9; int tap = r % 9;
        cw[t * 1825 + 25 + (9 + co) * 72 + ci * 9 + tap] = ld_in(aow, idx, bf);
    }
    for (int idx = tid; idx < TT * 9; idx += stp)
        cw[(idx / 9) * 1825 + (idx % 9)] = ld_in(awb, idx, bf);
    for (int idx = tid; idx < TT * 16; idx += stp)
        cw[(idx / 16) * 1825 + 9 + (idx % 16)] = ld_in(aob, idx, bf);

    float* tw = ws + WS_TW;
    for (int i = tid; i < 18; i += stp) tw[i] = ld_in(projw, i, bf);
    for (int i = tid; i < 6; i += stp) {
        float sc = ld_in(bng, i, bf) * rsqrtf(ld_in(bnv, i, bf) + 1e-5f);
        tw[18 + i] = sc;
        tw[24 + i] = ld_in(bnb, i, bf) - ld_in(bnm, i, bf) * sc;
    }
    for (int i = tid; i < 22;  i += stp) tw[32  + i] = ld_in(l0w, i, bf);
    for (int i = tid; i < 22;  i += stp) tw[54  + i] = ld_in(l0b, i, bf);
    for (int i = tid; i < 198; i += stp) tw[76  + i] = ld_in(lsw, i, bf);
    for (int i = tid; i < 22;  i += stp) tw[274 + i] = ld_in(lsb, i, bf);
    for (int i = tid; i < 242; i += stp) tw[296 + i] = ld_in(l1w, i, bf);
    for (int i = tid; i < 11;  i += stp) tw[538 + i] = ld_in(l1b, i, bf);
    for (int i = tid; i < 242; i += stp) tw[549 + i] = ld_in(l2w, i, bf);
    for (int i = tid; i < 11;  i += stp) tw[791 + i] = ld_in(l2b, i, bf);
    for (int i = tid; i < 36;  i += stp) tw[802 + i] = ld_in(sqw, i, bf);
    for (int i = tid; i < 2;   i += stp) tw[838 + i] = ld_in(sqb, i, bf);
    for (int i = tid; i < 33;  i += stp) tw[840 + i] = ld_in(lcw, i, bf);
    for (int i = tid; i < 3;   i += stp) tw[873 + i] = ld_in(lcb, i, bf);
}

// ---------------- fused MFMA conv + deformable sampling (512 threads) ----------------
__device__ inline float samp(const float* __restrict__ src, int y, int x) {
    bool valid = (y >= 0) & (y < HH) & (x >= 0) & (x < WW);
    int yc = min(max(y, 0), HH - 1);
    int xc = min(max(x, 0), WW - 1);
    float v = src[yc * WW + xc];
    return valid ? v : 0.0f;
}

// K-chunk c = dy; within chunk k = (g,j): ci = 2g + (j>>2), dx = j&3 (dx==3 pad).
// C/D layout: col(channel)=lane&15, row(pixel)=(lane>>4)*4+reg  (HW-verified).
// 8 waves; wave owns tile row py=wave (2 M-tiles m=0,1; px = m*16 + rowidx).
__global__ __launch_bounds__(512) void dcn_fused(
        const void* __restrict__ guid, const int* __restrict__ flagp,
        const float* __restrict__ wts,
        const float* __restrict__ src, float* __restrict__ dst, int t) {
    __shared__ unsigned int hal[8][10][36];   // (hi|lo<<16) packed bf16 pair
    __shared__ float outb[8][32][26];         // per-wave private redistribution
    const int bf = *flagp;
    const int bx = blockIdx.x % 38, by = blockIdx.x / 38;
    const int x0 = bx * 32, y0 = by * 8;
    for (int idx = threadIdx.x; idx < 8 * 360; idx += 512) {
        int ci = idx / 360; int r = (idx % 360) / 36; int c = idx % 36;
        int gy = y0 - 1 + r, gx = x0 - 1 + c;
        float v = 0.f;
        if (c < 34 && gy >= 0 && gy < HH && gx >= 0 && gx < WW)
            v = ld_in(guid, (long long)(t * 8 + ci) * HWSZ + gy * WW + gx, bf);
        hal[ci][r][c] = bfsplit_pack(v);
    }
    const int lane = threadIdx.x & 63;
    const int wave = threadIdx.x >> 6;
    const int col = lane & 15, g = lane >> 4;

    // B fragments (weights): Bh/Bl[Ntile][chunk] (identical across waves)
    FU Bh[2][3], Bl[2][3];
#pragma unroll
    for (int Nt = 0; Nt < 2; ++Nt)
#pragma unroll
    for (int c = 0; c < 3; ++c) {
        unsigned short eh[8], el[8];
#pragma unroll
        for (int j = 0; j < 8; ++j) {
            int ci = 2 * g + (j >> 2), dx = j & 3;
            int cc = Nt * 16 + col;
            float w = 0.f;
            if (cc < 25 && dx < 3) w = wts[25 + cc * 72 + ci * 9 + c * 3 + dx];
            unsigned int pk = bfsplit_pack(w);
            eh[j] = (unsigned short)(pk & 0xFFFFu);
            el[j] = (unsigned short)(pk >> 16);
        }
#pragma unroll
        for (int q = 0; q < 4; ++q) {
            Bh[Nt][c].u[q] = (unsigned int)eh[2*q] | ((unsigned int)eh[2*q+1] << 16);
            Bl[Nt][c].u[q] = (unsigned int)el[2*q] | ((unsigned int)el[2*q+1] << 16);
        }
    }
    __syncthreads();

    const float* bias = wts;
#pragma unroll
    for (int m = 0; m < 2; ++m) {
        const int pxx = m * 16 + col;          // this lane's A-row pixel (x offset)
        FU Ah[3], Al[3];
#pragma unroll
        for (int c = 0; c < 3; ++c) {
            const unsigned int* r0 = &hal[2 * g][wave + c][pxx];
            const unsigned int* r1 = &hal[2 * g + 1][wave + c][pxx];
            unsigned int q0 = r0[0], q1 = r0[1], q2 = r0[2], q3 = r0[3];
            unsigned int q4 = r1[0], q5 = r1[1], q6 = r1[2], q7 = r1[3];
            Ah[c].u[0] = __builtin_amdgcn_perm(q1, q0, 0x05040100u);
            Ah[c].u[1] = __builtin_amdgcn_perm(q3, q2, 0x05040100u);
            Ah[c].u[2] = __builtin_amdgcn_perm(q5, q4, 0x05040100u);
            Ah[c].u[3] = __builtin_amdgcn_perm(q7, q6, 0x05040100u);
            Al[c].u[0] = __builtin_amdgcn_perm(q1, q0, 0x07060302u);
            Al[c].u[1] = __builtin_amdgcn_perm(q3, q2, 0x07060302u);
            Al[c].u[2] = __builtin_amdgcn_perm(q5, q4, 0x07060302u);
            Al[c].u[3] = __builtin_amdgcn_perm(q7, q6, 0x07060302u);
        }
#pragma unroll
        for (int Nt = 0; Nt < 2; ++Nt) {
            f32x4 acc = {0.f, 0.f, 0.f, 0.f};
#pragma unroll
            for (int c = 0; c < 3; ++c) {
                acc = __builtin_amdgcn_mfma_f32_16x16x32_bf16(Ah[c].v, Bh[Nt][c].v, acc, 0, 0, 0);
                acc = __builtin_amdgcn_mfma_f32_16x16x32_bf16(Al[c].v, Bh[Nt][c].v, acc, 0, 0, 0);
                acc = __builtin_amdgcn_mfma_f32_16x16x32_bf16(Ah[c].v, Bl[Nt][c].v, acc, 0, 0, 0);
            }
            const int co = Nt * 16 + col;
            if (co < 25) {
                float bs = bias[co];
#pragma unroll
                for (int r = 0; r < 4; ++r)
                    outb[wave][m * 16 + g * 4 + r][co] = acc[r] + bs;
            }
        }
    }
    // outb is wave-private: same-wave LDS RAW is ordered by lgkmcnt, no barrier.
    {
        const int half = lane >> 5;
        const int pxl = lane & 31;
        const int gy = y0 + wave, gx = x0 + pxl;
        float v[25];
#pragma unroll
        for (int c = 0; c < 25; ++c) v[c] = outb[wave][pxl][c];
        float w9[9], s = 0.f;
#pragma unroll
        for (int k = 0; k < 9; ++k) { w9[k] = 1.f / (1.f + __expf(-v[k])); s += w9[k]; }
        const float inv = 1.f / (s + 1e-8f);
        float out = 0.f;
#pragma unroll
        for (int tp = 0; tp < 5; ++tp) {
            const int ka = tp;                 // half 0 taps 0..4
            const int kb = tp + 5;             // half 1 taps 5..8 (kb==9 invalid)
            const bool vb = (kb < 9);
            // per-lane tap params, all compile-time register selects
            float wa = w9[ka] * inv;
            float wb = vb ? w9[kb < 9 ? kb : 8] * inv : 0.f;
            float w  = half ? wb : wa;
            const int kpa = (ka < 4) ? ka : ka - 1;
            const int kpb = vb ? ((kb < 4) ? kb : kb - 1) : 0;
            float oya = (ka == 4) ? 0.f : v[9 + 2 * kpa];
            float oxa = (ka == 4) ? 0.f : v[10 + 2 * kpa];
            float oyb = vb ? v[9 + 2 * kpb] : 0.f;
            float oxb = vb ? v[10 + 2 * kpb] : 0.f;
            float oy = half ? oyb : oya;
            float ox = half ? oxb : oxa;
            const int dya = ka / 3 - 1, dxa = ka % 3 - 1;
            const int dyb = vb ? kb / 3 - 1 : 0, dxb = vb ? kb % 3 - 1 : 0;
            int dy = half ? dyb : dya;
            int dx = half ? dxb : dxa;
            float ys = (float)(gy + dy) + oy;
            float xs = (float)(gx + dx) + ox;
            float yf = floorf(ys), xf = floorf(xs);
            float wy = ys - yf, wx = xs - xf;
            int yi = (int)yf, xi = (int)xf;
            float v00 = samp(src, yi, xi);
            float v01 = samp(src, yi, xi + 1);
            float v10 = samp(src, yi + 1, xi);
            float v11 = samp(src, yi + 1, xi + 1);
            float sv = v00 * (1.f - wy) * (1.f - wx) + v01 * (1.f - wy) * wx
                     + v10 * wy * (1.f - wx) + v11 * wy * wx;
            out = fmaf(w, sv, out);
        }
        out += __shfl_xor(out, 32);
        if (half == 0) dst[gy * WW + gx] = out;
    }
}

// ---------------- tail helpers ----------------
// stage a1 (attn*w+b for c<16) tiles + feats tiles; caller syncs, then sf fill.
__device__ inline void stage_a1_ft(const void* attn, int bf, const float* tw,
                                   const float* feats, float (*a1t)[10][34],
                                   float (*ft)[10][34], int x0, int y0) {
    for (int idx = threadIdx.x; idx < 19 * 340; idx += 256) {
        int plane = idx / 340; int r = (idx % 340) / 34; int cc = idx % 34;
        int gy = y0 - 1 + r, gx = x0 - 1 + cc;
        bool ok = (gy >= 0 && gy < HH && gx >= 0 && gx < WW);
        if (plane < 16) {
            float x = ok ? ld_in(attn, (long long)plane * HWSZ + gy * WW + gx, bf) : 0.f;
            a1t[plane][r][cc] = ok ? fmaf(x, tw[32 + plane], tw[54 + plane]) : 0.f;
        } else {
            ft[plane - 16][r][cc] = ok ? feats[(long long)(3 + plane - 16) * HWSZ + gy * WW + gx] : 0.f;
        }
    }
}

__device__ inline void fill_sf(const float* tw, float (*a1t)[10][34],
                               const float (*ft)[10][34], int x0, int y0) {
    for (int idx = threadIdx.x; idx < 6 * 340; idx += 256) {
        int j = idx / 340; int r = (idx % 340) / 34; int cc = idx % 34;
        int gy = y0 - 1 + r, gx = x0 - 1 + cc;
        bool ok = (gy >= 0 && gy < HH && gx >= 0 && gx < WW);
        float o = 0.f;
        if (ok) {
            float f0 = ft[0][r][cc], f1 = ft[1][r][cc], f2 = ft[2][r][cc];
            float v = tw[j * 3 + 0] * f0 + tw[j * 3 + 1] * f1 + tw[j * 3 + 2] * f2;
            v = v * tw[18 + j] + tw[24 + j];
            v = (v >= 0.f) ? v : 0.2f * v;
            o = fmaf(v, tw[32 + 16 + j], tw[54 + 16 + j]);
        }
        a1t[16 + j][r][cc] = o;
    }
}

__device__ inline void lsk_acc(const float (*a1t)[10][34], const float* tw,
                               int lx, int ly, float* acc1, float* acc2) {
#pragma unroll
    for (int j = 0; j < 11; ++j) { acc1[j] = tw[538 + j]; acc2[j] = tw[791 + j]; }
    for (int c = 0; c < 22; ++c) {
        float a1c = a1t[c][ly + 1][lx + 1];
        float a2c = tw[274 + c];
#pragma unroll
        for (int dy = 0; dy < 3; ++dy)
#pragma unroll
        for (int dx = 0; dx < 3; ++dx)
            a2c = fmaf(a1t[c][ly + dy][lx + dx], tw[76 + c * 9 + dy * 3 + dx], a2c);
#pragma unroll
        for (int j = 0; j < 11; ++j) {
            acc1[j] = fmaf(a1c, tw[296 + j * 22 + c], acc1[j]);
            acc2[j] = fmaf(a2c, tw[549 + j * 22 + c], acc2[j]);
        }
    }
}

// ---------------- tailA: compute agg (mean/max over 22 ch) ----------------
__global__ __launch_bounds__(256) void tailA(
        const void* __restrict__ attn, const int* __restrict__ flagp,
        const float* __restrict__ tw, const float* __restrict__ feats,
        float* __restrict__ agg) {
    __shared__ float a1t[22][10][34];
    __shared__ float ft[3][10][34];
    const int bf = *flagp;
    const int bx = blockIdx.x % 38, by = blockIdx.x / 38;
    const int x0 = bx * 32, y0 = by * 8;
    stage_a1_ft(attn, bf, tw, feats, a1t, ft, x0, y0);
    __syncthreads();
    fill_sf(tw, a1t, ft, x0, y0);
    __syncthreads();
    const int lx = threadIdx.x & 31, ly = threadIdx.x >> 5;
    float acc1[11], acc2[11];
    lsk_acc(a1t, tw, lx, ly, acc1, acc2);
    float s = 0.f, mx = -1e30f;
#pragma unroll
    for (int j = 0; j < 11; ++j) {
        s += acc1[j] + acc2[j];
        mx = fmaxf(mx, fmaxf(acc1[j], acc2[j]));
    }
    const int p = (y0 + ly) * WW + x0 + lx;
    agg[p] = s * (1.0f / 22.0f);
    agg[HWSZ + p] = mx;
}

// ---------------- tailB: recompute acc, sq-gate, project, output ----------------
__global__ __launch_bounds__(256) void tailB(
        const void* __restrict__ attn, const int* __restrict__ flagp,
        const float* __restrict__ tw, const float* __restrict__ feats,
        const float* __restrict__ agg, void* __restrict__ out) {
    __shared__ float a1t[22][10][34];
    __shared__ float ft[3][10][34];
    __shared__ float gt[2][10][34];
    const int bf = *flagp;
    const int bx = blockIdx.x % 38, by = blockIdx.x / 38;
    const int x0 = bx * 32, y0 = by * 8;
    stage_a1_ft(attn, bf, tw, feats, a1t, ft, x0, y0);
    for (int idx = threadIdx.x; idx < 2 * 340; idx += 256) {
        int plane = idx / 340; int r = (idx % 340) / 34; int cc = idx % 34;
        int gy = y0 - 1 + r, gx = x0 - 1 + cc;
        bool ok = (gy >= 0 && gy < HH && gx >= 0 && gx < WW);
        gt[plane][r][cc] = ok ? agg[(long long)plane * HWSZ + gy * WW + gx] : 0.f;
    }
    __syncthreads();
    fill_sf(tw, a1t, ft, x0, y0);
    __syncthreads();
    const int lx = threadIdx.x & 31, ly = threadIdx.x >> 5;
    float acc1[11], acc2[11];
    lsk_acc(a1t, tw, lx, ly, acc1, acc2);
    float s0 = tw[838], s1 = tw[839];
#pragma unroll
    for (int dy = 0; dy < 3; ++dy)
#pragma unroll
    for (int dx = 0; dx < 3; ++dx) {
        float v0 = gt[0][ly + dy][lx + dx], v1 = gt[1][ly + dy][lx + dx];
        s0 = fmaf(v0, tw[802 + 0 * 18 + 0 * 9 + dy * 3 + dx], s0);
        s0 = fmaf(v1, tw[802 + 0 * 18 + 1 * 9 + dy * 3 + dx], s0);
        s1 = fmaf(v0, tw[802 + 1 * 18 + 0 * 9 + dy * 3 + dx], s1);
        s1 = fmaf(v1, tw[802 + 1 * 18 + 1 * 9 + dy * 3 + dx], s1);
    }
    float sg0 = 1.0f / (1.0f + __expf(-s0));
    float sg1 = 1.0f / (1.0f + __expf(-s1));
    float at3[3] = { tw[873], tw[874], tw[875] };
#pragma unroll
    for (int j = 0; j < 11; ++j) {
        float at = acc1[j] * sg0 + acc2[j] * sg1;
#pragma unroll
        for (int i = 0; i < 3; ++i) at3[i] = fmaf(at, tw[840 + i * 11 + j], at3[i]);
    }
    float o = ft[0][ly + 1][lx + 1] * at3[0] + ft[1][ly + 1][lx + 1] * at3[1]
            + ft[2][ly + 1][lx + 1] * at3[2];
    const int p = (y0 + ly) * WW + x0 + lx;
    if (bf) ((__hip_bfloat16*)out)[p] = __float2bfloat16(o);
    else    ((float*)out)[p] = o;
}

// ---------------- host ----------------
extern "C" void kernel_launch(void* const* d_in, const int* in_sizes, int n_in,
                              void* d_out, int out_size, void* d_ws, size_t ws_size,
                              hipStream_t stream) {
    (void)in_sizes; (void)n_in; (void)out_size; (void)ws_size;
    float* WSF = (float*)d_ws;
    const int* flagp = (const int*)d_ws;
    float* cw   = WSF + WS_CW;
    float* tw   = WSF + WS_TW;
    float* FB   = WSF + WS_FB;             // 7 planes
    float* AGG  = FB + 7 * HWSZ;           // 2 planes

    prep_all<<<1672, 256, 0, stream>>>(d_in[0], d_in[1],
        d_in[4], d_in[5], d_in[6], d_in[7],
        d_in[8], d_in[9], d_in[10], d_in[11], d_in[12],
        d_in[13], d_in[14], d_in[15], d_in[16],
        d_in[17], d_in[18], d_in[19], d_in[20],
        d_in[21], d_in[22], d_in[23], d_in[24], WSF);

    for (int t = 0; t < 6; ++t) {
        const float* src = (t == 0) ? (FB + 6 * HWSZ) : (FB + (t - 1) * HWSZ);
        dcn_fused<<<44 * 38, 512, 0, stream>>>(d_in[1], flagp, cw + t * 1825, src, FB + t * HWSZ, t);
    }
    tailA<<<44 * 38, 256, 0, stream>>>(d_in[2], flagp, tw, FB, AGG);
    tailB<<<44 * 38, 256, 0, stream>>>(d_in[2], flagp, tw, FB, AGG, d_out);
}

// Round 6
// 464.587 us; speedup vs baseline: 1.2648x; 1.2648x over previous
//
#include <hip/hip_runtime.h>
#include <hip/hip_bf16.h>

#define HH 352
#define WW 1216
#define HWSZ (HH * WW)   // 428032
#define TT 6

// ---------------- workspace layout (in floats) ----------------
#define WS_CW   16
#define WS_TW   11008
#define WS_FB   12032

typedef __attribute__((ext_vector_type(4))) float f32x4;
typedef __attribute__((ext_vector_type(8))) short s16x8;
union FU { unsigned int u[4]; s16x8 v; };

__device__ inline float ld_in(const void* p, long long i, int bf) {
    return bf ? __bfloat162float(((const __hip_bfloat16*)p)[i]) : ((const float*)p)[i];
}

// split v into bf16 hi (low16) + bf16 lo (high16), RNE
__device__ inline unsigned int bfsplit_pack(float v) {
    unsigned int uv = __float_as_uint(v);
    unsigned int h = (uv + 0x7FFFu + ((uv >> 16) & 1u)) >> 16;
    float hf = __uint_as_float(h << 16);
    float r = v - hf;
    unsigned int ur = __float_as_uint(r);
    unsigned int l = (ur + 0x7FFFu + ((ur >> 16) & 1u)) >> 16;
    return (h & 0xFFFFu) | (l << 16);
}

__device__ inline int detect_mode(const void* guid) {
    const unsigned int* u = (const unsigned int*)guid;
    int cnt = 0;
    for (int i = 0; i < 128; ++i) {
        unsigned int lo = u[i] & 0xFFFFu;
        int e = (int)((lo >> 7) & 0xFF);
        if (e >= 110 && e <= 140) cnt++;
    }
    return (cnt >= 96) ? 1 : 0;
}

// ---------------- prep: dtype detect + weight repack + feat convert ----------------
__global__ __launch_bounds__(256) void prep_all(
        const void* feat_init, const void* guid,
        const void* aww, const void* awb, const void* aow, const void* aob,
        const void* projw, const void* bng, const void* bnb,
        const void* bnm, const void* bnv,
        const void* l0w, const void* l0b, const void* lsw, const void* lsb,
        const void* l1w, const void* l1b, const void* l2w, const void* l2b,
        const void* sqw, const void* sqb, const void* lcw, const void* lcb,
        float* ws) {
    __shared__ int smode;
    if (threadIdx.x == 0) {
        int mode = detect_mode(guid);
        smode = mode;
        if (blockIdx.x == 0) *(int*)ws = mode;
    }
    __syncthreads();
    const int bf = smode;
    {
        int i = blockIdx.x * 256 + threadIdx.x;
        if (i < HWSZ) ws[WS_FB + 6 * HWSZ + i] = ld_in(feat_init, i, bf);
    }
    if (blockIdx.x >= 32) return;
    const int tid = blockIdx.x * 256 + threadIdx.x;
    const int stp = 32 * 256;
    float* cw = ws + WS_CW;
    for (int idx = tid; idx < TT * 9 * 72; idx += stp) {
        int t = idx / 648; int r = idx % 648;
        int co = r / 72; int ci = (r % 72) / 9; int tap = r % 9;
        cw[t * 1825 + 25 + co * 72 + ci * 9 + tap] = ld_in(aww, idx, bf);
    }
    for (int idx = tid; idx < TT * 16 * 72; idx += stp) {
        int t = idx / 1152; int r = idx % 1152;
        int co = r / 72; int ci = (r % 72) / 9; int tap = r % 9;
        cw[t * 1825 + 25 + (9 + co) * 72 + ci * 9 + tap] = ld_in(aow, idx, bf);
    }
    for (int idx = tid; idx < TT * 9; idx += stp)
        cw[(idx / 9) * 1825 + (idx % 9)] = ld_in(awb, idx, bf);
    for (int idx = tid; idx < TT * 16; idx += stp)
        cw[(idx / 16) * 1825 + 9 + (idx % 16)] = ld_in(aob, idx, bf);

    float* tw = ws + WS_TW;
    for (int i = tid; i < 18; i += stp) tw[i] = ld_in(projw, i, bf);
    for (int i = tid; i < 6; i += stp) {
        float sc = ld_in(bng, i, bf) * rsqrtf(ld_in(bnv, i, bf) + 1e-5f);
        tw[18 + i] = sc;
        tw[24 + i] = ld_in(bnb, i, bf) - ld_in(bnm, i, bf) * sc;
    }
    for (int i = tid; i < 22;  i += stp) tw[32  + i] = ld_in(l0w, i, bf);
    for (int i = tid; i < 22;  i += stp) tw[54  + i] = ld_in(l0b, i, bf);
    for (int i = tid; i < 198; i += stp) tw[76  + i] = ld_in(lsw, i, bf);
    for (int i = tid; i < 22;  i += stp) tw[274 + i] = ld_in(lsb, i, bf);
    for (int i = tid; i < 242; i += stp) tw[296 + i] = ld_in(l1w, i, bf);
    for (int i = tid; i < 11;  i += stp) tw[538 + i] = ld_in(l1b, i, bf);
    for (int i = tid; i < 242; i += stp) tw[549 + i] = ld_in(l2w, i, bf);
    for (int i = tid; i < 11;  i += stp) tw[791 + i] = ld_in(l2b, i, bf);
    for (int i = tid; i < 36;  i += stp) tw[802 + i] = ld_in(sqw, i, bf);
    for (int i = tid; i < 2;   i += stp) tw[838 + i] = ld_in(sqb, i, bf);
    for (int i = tid; i < 33;  i += stp) tw[840 + i] = ld_in(lcw, i, bf);
    for (int i = tid; i < 3;   i += stp) tw[873 + i] = ld_in(lcb, i, bf);
}

// ---------------- fused MFMA conv + deformable sampling ----------------
__device__ inline float samp(const float* __restrict__ src, int y, int x) {
    bool valid = (y >= 0) & (y < HH) & (x >= 0) & (x < WW);
    int yc = min(max(y, 0), HH - 1);
    int xc = min(max(x, 0), WW - 1);
    float v = src[yc * WW + xc];
    return valid ? v : 0.0f;
}

// K-chunk c = dy; within chunk k=(g,j): ci=2g+(j>>2), dx=j&3 (dx==3 pad).
// C/D layout: col(channel)=lane&15, row(pixel)=(lane>>4)*4+reg (HW-verified).
// 4 waves; wave handles M-tiles M=wave*4+m: row py=M>>1, x-half (M&1)*16.
// Per-m finalize: 4 lanes/pixel (q=lane>>4) split 9 taps as tap=i*4+q, i<3;
// combine via shfl_xor(16/32).
__global__ __launch_bounds__(256) void dcn_fused(
        const void* __restrict__ guid, const int* __restrict__ flagp,
        const float* __restrict__ wts,
        const float* __restrict__ src, float* __restrict__ dst, int t) {
    __shared__ unsigned int hal[8][10][36];   // 11520 B
    __shared__ float outb[4][2][16][27];      // 13824 B (per-wave, m-parity dbuf)
    const int bf = *flagp;
    const int bx = blockIdx.x % 38, by = blockIdx.x / 38;
    const int x0 = bx * 32, y0 = by * 8;

    if (!bf) {
        // fp32: 16B-aligned float4 staging. Quad k covers global x = x0-4+4k .. +3,
        // dest col = 4k-3+e (halo col 0 == x0-1). All cols 0..35 written once.
        const float* gp = (const float*)guid + (long long)(t * 8) * HWSZ;
        for (int idx = threadIdx.x; idx < 800; idx += 256) {
            int ci = idx / 100; int rem = idx % 100; int rr = rem / 10; int k = rem % 10;
            int gy = y0 - 1 + rr;
            int gxb = x0 - 4 + 4 * k;
            float vx = 0.f, vy = 0.f, vz = 0.f, vw = 0.f;
            if (gy >= 0 && gy < HH) {
                const float* rowp = gp + (long long)ci * HWSZ + (long long)gy * WW;
                if (gxb >= 0 && gxb + 3 < WW) {
                    const float4 v4 = *(const float4*)(rowp + gxb);
                    vx = v4.x; vy = v4.y; vz = v4.z; vw = v4.w;
                } else {
                    if (gxb + 0 >= 0 && gxb + 0 < WW) vx = rowp[gxb + 0];
                    if (gxb + 1 >= 0 && gxb + 1 < WW) vy = rowp[gxb + 1];
                    if (gxb + 2 >= 0 && gxb + 2 < WW) vz = rowp[gxb + 2];
                    if (gxb + 3 >= 0 && gxb + 3 < WW) vw = rowp[gxb + 3];
                }
            }
            int c0 = 4 * k - 3;
            if (c0 + 0 >= 0 && c0 + 0 < 36) hal[ci][rr][c0 + 0] = bfsplit_pack(vx);
            if (c0 + 1 >= 0 && c0 + 1 < 36) hal[ci][rr][c0 + 1] = bfsplit_pack(vy);
            if (c0 + 2 >= 0 && c0 + 2 < 36) hal[ci][rr][c0 + 2] = bfsplit_pack(vz);
            if (c0 + 3 >= 0 && c0 + 3 < 36) hal[ci][rr][c0 + 3] = bfsplit_pack(vw);
        }
    } else {
        for (int idx = threadIdx.x; idx < 8 * 360; idx += 256) {
            int ci = idx / 360; int r = (idx % 360) / 36; int c = idx % 36;
            int gy = y0 - 1 + r, gx = x0 - 1 + c;
            float v = 0.f;
            if (c < 34 && gy >= 0 && gy < HH && gx >= 0 && gx < WW)
                v = ld_in(guid, (long long)(t * 8 + ci) * HWSZ + gy * WW + gx, bf);
            hal[ci][r][c] = bfsplit_pack(v);
        }
    }
    const int lane = threadIdx.x & 63;
    const int wave = threadIdx.x >> 6;
    const int col = lane & 15, g = lane >> 4;

    // B fragments (weights): Bh/Bl[Ntile][chunk]
    FU Bh[2][3], Bl[2][3];
#pragma unroll
    for (int Nt = 0; Nt < 2; ++Nt)
#pragma unroll
    for (int c = 0; c < 3; ++c) {
        unsigned short eh[8], el[8];
#pragma unroll
        for (int j = 0; j < 8; ++j) {
            int ci = 2 * g + (j >> 2), dx = j & 3;
            int cc = Nt * 16 + col;
            float w = 0.f;
            if (cc < 25 && dx < 3) w = wts[25 + cc * 72 + ci * 9 + c * 3 + dx];
            unsigned int pk = bfsplit_pack(w);
            eh[j] = (unsigned short)(pk & 0xFFFFu);
            el[j] = (unsigned short)(pk >> 16);
        }
#pragma unroll
        for (int q = 0; q < 4; ++q) {
            Bh[Nt][c].u[q] = (unsigned int)eh[2*q] | ((unsigned int)eh[2*q+1] << 16);
            Bl[Nt][c].u[q] = (unsigned int)el[2*q] | ((unsigned int)el[2*q+1] << 16);
        }
    }
    __syncthreads();

    const float* bias = wts;
#pragma unroll
    for (int m = 0; m < 4; ++m) {
        const int M = wave * 4 + m;
        const int py = M >> 1;
        const int xoff = (M & 1) * 16;
        const int pxx = xoff + col;
        FU Ah[3], Al[3];
#pragma unroll
        for (int c = 0; c < 3; ++c) {
            const unsigned int* r0 = &hal[2 * g][py + c][pxx];
            const unsigned int* r1 = &hal[2 * g + 1][py + c][pxx];
            unsigned int q0 = r0[0], q1 = r0[1], q2 = r0[2], q3 = r0[3];
            unsigned int q4 = r1[0], q5 = r1[1], q6 = r1[2], q7 = r1[3];
            Ah[c].u[0] = __builtin_amdgcn_perm(q1, q0, 0x05040100u);
            Ah[c].u[1] = __builtin_amdgcn_perm(q3, q2, 0x05040100u);
            Ah[c].u[2] = __builtin_amdgcn_perm(q5, q4, 0x05040100u);
            Ah[c].u[3] = __builtin_amdgcn_perm(q7, q6, 0x05040100u);
            Al[c].u[0] = __builtin_amdgcn_perm(q1, q0, 0x07060302u);
            Al[c].u[1] = __builtin_amdgcn_perm(q3, q2, 0x07060302u);
            Al[c].u[2] = __builtin_amdgcn_perm(q5, q4, 0x07060302u);
            Al[c].u[3] = __builtin_amdgcn_perm(q7, q6, 0x07060302u);
        }
#pragma unroll
        for (int Nt = 0; Nt < 2; ++Nt) {
            f32x4 acc = {0.f, 0.f, 0.f, 0.f};
#pragma unroll
            for (int c = 0; c < 3; ++c) {
                acc = __builtin_amdgcn_mfma_f32_16x16x32_bf16(Ah[c].v, Bh[Nt][c].v, acc, 0, 0, 0);
                acc = __builtin_amdgcn_mfma_f32_16x16x32_bf16(Al[c].v, Bh[Nt][c].v, acc, 0, 0, 0);
                acc = __builtin_amdgcn_mfma_f32_16x16x32_bf16(Ah[c].v, Bl[Nt][c].v, acc, 0, 0, 0);
            }
            const int co = Nt * 16 + col;
            if (co < 25) {
                float bs = bias[co];
#pragma unroll
                for (int r = 0; r < 4; ++r)
                    outb[wave][m & 1][g * 4 + r][co] = acc[r] + bs;
            }
        }
        // per-m finalize: 16 pixels, 4 lanes each (quad q=g), taps tap=i*4+q
        {
            const int px = col;
            const int gy = y0 + py;
            const int gx = x0 + xoff + px;
            const float* ob = &outb[wave][m & 1][px][0];
            float sg[3], oyv[3], oxv[3];
            float psum = 0.f;
#pragma unroll
            for (int i = 0; i < 3; ++i) {
                int tap = i * 4 + g;
                bool valid = tap < 9;
                int tc = valid ? tap : 8;
                float wv = ob[tc];
                float sgv = 1.f / (1.f + __expf(-wv));
                sg[i] = valid ? sgv : 0.f;
                psum += sg[i];
                int kp = (tap < 4) ? tap : tap - 1;
                kp = min(kp, 7);
                float oy = ob[9 + 2 * kp];
                float ox = ob[10 + 2 * kp];
                bool use_off = valid && (tap != 4);
                oyv[i] = use_off ? oy : 0.f;
                oxv[i] = use_off ? ox : 0.f;
            }
            psum += __shfl_xor(psum, 16);
            psum += __shfl_xor(psum, 32);
            const float inv = 1.f / (psum + 1e-8f);
            float out = 0.f;
#pragma unroll
            for (int i = 0; i < 3; ++i) {
                int tap = min(i * 4 + g, 8);
                float w = sg[i] * inv;
                int d3 = tap / 3;
                int dy = d3 - 1, dx = tap - 3 * d3 - 1;
                float ys = (float)(gy + dy) + oyv[i];
                float xs = (float)(gx + dx) + oxv[i];
                float yf = floorf(ys), xf = floorf(xs);
                float wy = ys - yf, wx = xs - xf;
                int yi = (int)yf, xi = (int)xf;
                float v00 = samp(src, yi, xi);
                float v01 = samp(src, yi, xi + 1);
                float v10 = samp(src, yi + 1, xi);
                float v11 = samp(src, yi + 1, xi + 1);
                float sv = v00 * (1.f - wy) * (1.f - wx) + v01 * (1.f - wy) * wx
                         + v10 * wy * (1.f - wx) + v11 * wy * wx;
                out = fmaf(w, sv, out);
            }
            out += __shfl_xor(out, 16);
            out += __shfl_xor(out, 32);
            if (g == 0) dst[gy * WW + gx] = out;
        }
    }
}

// ---------------- tail (round-4 known-good) ----------------
__global__ __launch_bounds__(256) void tail1(
        const void* __restrict__ attn, const int* __restrict__ flagp,
        const float* __restrict__ tw, const float* __restrict__ feats,
        float* __restrict__ a1) {
    const int bf = *flagp;
    const int p = blockIdx.x * 256 + threadIdx.x;
    float x3[3] = { feats[3 * HWSZ + p], feats[4 * HWSZ + p], feats[5 * HWSZ + p] };
    float sf[6];
#pragma unroll
    for (int j = 0; j < 6; ++j) {
        float v = tw[j * 3 + 0] * x3[0] + tw[j * 3 + 1] * x3[1] + tw[j * 3 + 2] * x3[2];
        v = v * tw[18 + j] + tw[24 + j];
        sf[j] = (v >= 0.0f) ? v : 0.2f * v;
    }
#pragma unroll
    for (int c = 0; c < 22; ++c) {
        float x = (c < 16) ? ld_in(attn, (long long)c * HWSZ + p, bf) : sf[c - 16];
        a1[c * HWSZ + p] = fmaf(x, tw[32 + c], tw[54 + c]);
    }
}

__global__ __launch_bounds__(256) void tail2(
        const float* __restrict__ tw, const float* __restrict__ a1,
        float* __restrict__ a11, float* __restrict__ a21, float* __restrict__ agg) {
    __shared__ float tile[10][34];
    const int bx = blockIdx.x % 38, by = blockIdx.x / 38;
    const int x0 = bx * 32, y0 = by * 8;
    const int lx = threadIdx.x % 32, ly = threadIdx.x / 32;
    float acc1[11], acc2[11];
#pragma unroll
    for (int j = 0; j < 11; ++j) { acc1[j] = tw[538 + j]; acc2[j] = tw[791 + j]; }
    for (int c = 0; c < 22; ++c) {
        __syncthreads();
        for (int idx = threadIdx.x; idx < 340; idx += 256) {
            int r = idx / 34, cc = idx % 34;
            int gy = y0 - 1 + r, gx = x0 - 1 + cc;
            tile[r][cc] = (gy >= 0 && gy < HH && gx >= 0 && gx < WW)
                          ? a1[c * HWSZ + gy * WW + gx] : 0.0f;
        }
        __syncthreads();
        float a1c = tile[ly + 1][lx + 1];
        float a2c = tw[274 + c];
#pragma unroll
        for (int dy = 0; dy < 3; ++dy)
#pragma unroll
            for (int dx = 0; dx < 3; ++dx)
                a2c = fmaf(tile[ly + dy][lx + dx], tw[76 + c * 9 + dy * 3 + dx], a2c);
#pragma unroll
        for (int j = 0; j < 11; ++j) {
            acc1[j] = fmaf(a1c, tw[296 + j * 22 + c], acc1[j]);
            acc2[j] = fmaf(a2c, tw[549 + j * 22 + c], acc2[j]);
        }
    }
    const int p = (y0 + ly) * WW + x0 + lx;
    float s = 0.0f, mx = -1e30f;
#pragma unroll
    for (int j = 0; j < 11; ++j) {
        a11[j * HWSZ + p] = acc1[j];
        a21[j * HWSZ + p] = acc2[j];
        s += acc1[j] + acc2[j];
        mx = fmaxf(mx, fmaxf(acc1[j], acc2[j]));
    }
    agg[p] = s * (1.0f / 22.0f);
    agg[HWSZ + p] = mx;
}

__global__ __launch_bounds__(256) void tail3(
        const int* __restrict__ flagp, const float* __restrict__ tw,
        const float* __restrict__ feats,
        const float* __restrict__ a11, const float* __restrict__ a21,
        const float* __restrict__ agg, void* __restrict__ out) {
    __shared__ float t0[10][34], t1[10][34];
    const int bx = blockIdx.x % 38, by = blockIdx.x / 38;
    const int x0 = bx * 32, y0 = by * 8;
    for (int idx = threadIdx.x; idx < 340; idx += 256) {
        int r = idx / 34, cc = idx % 34;
        int gy = y0 - 1 + r, gx = x0 - 1 + cc;
        bool ok = (gy >= 0 && gy < HH && gx >= 0 && gx < WW);
        t0[r][cc] = ok ? agg[gy * WW + gx] : 0.0f;
        t1[r][cc] = ok ? agg[HWSZ + gy * WW + gx] : 0.0f;
    }
    __syncthreads();
    const int lx = threadIdx.x % 32, ly = threadIdx.x / 32;
    float s0 = tw[838], s1 = tw[839];
#pragma unroll
    for (int dy = 0; dy < 3; ++dy)
#pragma unroll
        for (int dx = 0; dx < 3; ++dx) {
            float v0 = t0[ly + dy][lx + dx], v1 = t1[ly + dy][lx + dx];
            s0 = fmaf(v0, tw[802 + 0 * 18 + 0 * 9 + dy * 3 + dx], s0);
            s0 = fmaf(v1, tw[802 + 0 * 18 + 1 * 9 + dy * 3 + dx], s0);
            s1 = fmaf(v0, tw[802 + 1 * 18 + 0 * 9 + dy * 3 + dx], s1);
            s1 = fmaf(v1, tw[802 + 1 * 18 + 1 * 9 + dy * 3 + dx], s1);
        }
    float sg0 = 1.0f / (1.0f + __expf(-s0));
    float sg1 = 1.0f / (1.0f + __expf(-s1));
    const int p = (y0 + ly) * WW + x0 + lx;
    float at3[3] = { tw[873], tw[874], tw[875] };
#pragma unroll
    for (int j = 0; j < 11; ++j) {
        float at = a11[j * HWSZ + p] * sg0 + a21[j * HWSZ + p] * sg1;
#pragma unroll
        for (int i = 0; i < 3; ++i) at3[i] = fmaf(at, tw[840 + i * 11 + j], at3[i]);
    }
    float o = feats[3 * HWSZ + p] * at3[0] + feats[4 * HWSZ + p] * at3[1]
            + feats[5 * HWSZ + p] * at3[2];
    int bf = *flagp;
    if (bf) ((__hip_bfloat16*)out)[p] = __float2bfloat16(o);
    else    ((float*)out)[p] = o;
}

// ---------------- host ----------------
extern "C" void kernel_launch(void* const* d_in, const int* in_sizes, int n_in,
                              void* d_out, int out_size, void* d_ws, size_t ws_size,
                              hipStream_t stream) {
    (void)in_sizes; (void)n_in; (void)out_size; (void)ws_size;
    float* WSF = (float*)d_ws;
    const int* flagp = (const int*)d_ws;
    float* cw   = WSF + WS_CW;
    float* tw   = WSF + WS_TW;
    float* FB   = WSF + WS_FB;             // 7 planes
    float* A1   = FB + 7 * HWSZ;           // 22 planes
    float* A11  = A1 + 22 * HWSZ;          // 11 planes
    float* A21  = A11 + 11 * HWSZ;         // 11 planes
    float* AGG  = A21 + 11 * HWSZ;         // 2 planes

    prep_all<<<1672, 256, 0, stream>>>(d_in[0], d_in[1],
        d_in[4], d_in[5], d_in[6], d_in[7],
        d_in[8], d_in[9], d_in[10], d_in[11], d_in[12],
        d_in[13], d_in[14], d_in[15], d_in[16],
        d_in[17], d_in[18], d_in[19], d_in[20],
        d_in[21], d_in[22], d_in[23], d_in[24], WSF);

    for (int t = 0; t < 6; ++t) {
        const float* src = (t == 0) ? (FB + 6 * HWSZ) : (FB + (t - 1) * HWSZ);
        dcn_fused<<<44 * 38, 256, 0, stream>>>(d_in[1], flagp, cw + t * 1825, src, FB + t * HWSZ, t);
    }
    tail1<<<HWSZ / 256, 256, 0, stream>>>(d_in[2], flagp, tw, FB, A1);
    tail2<<<44 * 38, 256, 0, stream>>>(tw, A1, A11, A21, AGG);
    tail3<<<44 * 38, 256, 0, stream>>>(flagp, tw, FB, A11, A21, AGG, d_out);
}

// Round 7
// 404.349 us; speedup vs baseline: 1.4533x; 1.1490x over previous
//
#include <hip/hip_runtime.h>
#include <hip/hip_bf16.h>

#define HH 352
#define WW 1216
#define HWSZ (HH * WW)   // 428032
#define TT 6

// ---------------- workspace layout (in floats) ----------------
// [0]          : int mode flag (1 = bf16 inputs, 0 = fp32 inputs)
// WS_CW  16    : conv biases, per t: 32 floats (25 used)
// WS_TW  11008 : tail weights (876 floats)
// WS_BF  12032 : B-fragments, per t: 768 uint4 (2Nt x 3c x {hi,lo} x 64 lanes)
// WS_FB  30464 : FB 7 planes; then A11 11, A21 11, AGG 2
#define WS_CW   16
#define WS_TW   11008
#define WS_BF   12032
#define WS_FB   30464

typedef __attribute__((ext_vector_type(4))) float f32x4;
typedef __attribute__((ext_vector_type(8))) short s16x8;
union FU { unsigned int u[4]; s16x8 v; };

__device__ inline float ld_in(const void* p, long long i, int bf) {
    return bf ? __bfloat162float(((const __hip_bfloat16*)p)[i]) : ((const float*)p)[i];
}

// split v into bf16 hi (low16) + bf16 lo (high16), RNE
__device__ inline unsigned int bfsplit_pack(float v) {
    unsigned int uv = __float_as_uint(v);
    unsigned int h = (uv + 0x7FFFu + ((uv >> 16) & 1u)) >> 16;
    float hf = __uint_as_float(h << 16);
    float r = v - hf;
    unsigned int ur = __float_as_uint(r);
    unsigned int l = (ur + 0x7FFFu + ((ur >> 16) & 1u)) >> 16;
    return (h & 0xFFFFu) | (l << 16);
}

__device__ inline int detect_mode(const void* guid) {
    const unsigned int* u = (const unsigned int*)guid;
    int cnt = 0;
    for (int i = 0; i < 128; ++i) {
        unsigned int lo = u[i] & 0xFFFFu;
        int e = (int)((lo >> 7) & 0xFF);
        if (e >= 110 && e <= 140) cnt++;
    }
    return (cnt >= 96) ? 1 : 0;
}

// ---------------- prep: dtype detect + weight repack + B-frag build ----------------
__global__ __launch_bounds__(256) void prep_all(
        const void* feat_init, const void* guid,
        const void* aww, const void* awb, const void* aow, const void* aob,
        const void* projw, const void* bng, const void* bnb,
        const void* bnm, const void* bnv,
        const void* l0w, const void* l0b, const void* lsw, const void* lsb,
        const void* l1w, const void* l1b, const void* l2w, const void* l2b,
        const void* sqw, const void* sqb, const void* lcw, const void* lcb,
        float* ws) {
    __shared__ int smode;
    if (threadIdx.x == 0) {
        int mode = detect_mode(guid);
        smode = mode;
        if (blockIdx.x == 0) *(int*)ws = mode;
    }
    __syncthreads();
    const int bf = smode;
    {
        int i = blockIdx.x * 256 + threadIdx.x;
        if (i < HWSZ) ws[WS_FB + 6 * HWSZ + i] = ld_in(feat_init, i, bf);
    }
    if (blockIdx.x >= 32) return;
    const int tid = blockIdx.x * 256 + threadIdx.x;
    const int stp = 32 * 256;

    // biases: cw[t*32 + co]
    float* cw = ws + WS_CW;
    for (int idx = tid; idx < TT * 9; idx += stp)
        cw[(idx / 9) * 32 + (idx % 9)] = ld_in(awb, idx, bf);
    for (int idx = tid; idx < TT * 16; idx += stp)
        cw[(idx / 16) * 32 + 9 + (idx % 16)] = ld_in(aob, idx, bf);

    // B-fragments: per (t, Nt, c, lane) build hi/lo uint4
    uint4* bfb = (uint4*)(ws + WS_BF);
    for (int idx = tid; idx < TT * 2 * 3 * 64; idx += stp) {
        int t = idx / 384; int r = idx % 384;
        int Nt = r / 192; int r2 = r % 192;
        int c = r2 / 64; int lane = r2 % 64;
        int col = lane & 15, g = lane >> 4;
        unsigned short eh[8], el[8];
#pragma unroll
        for (int j = 0; j < 8; ++j) {
            int ci = 2 * g + (j >> 2), dx = j & 3;
            int cc = Nt * 16 + col;
            float w = 0.f;
            if (cc < 25 && dx < 3) {
                if (cc < 9) w = ld_in(aww, (long long)(((t * 9 + cc) * 8 + ci) * 9 + c * 3 + dx), bf);
                else        w = ld_in(aow, (long long)(((t * 16 + (cc - 9)) * 8 + ci) * 9 + c * 3 + dx), bf);
            }
            unsigned int pk = bfsplit_pack(w);
            eh[j] = (unsigned short)(pk & 0xFFFFu);
            el[j] = (unsigned short)(pk >> 16);
        }
        uint4 H, L;
        H.x = (unsigned int)eh[0] | ((unsigned int)eh[1] << 16);
        H.y = (unsigned int)eh[2] | ((unsigned int)eh[3] << 16);
        H.z = (unsigned int)eh[4] | ((unsigned int)eh[5] << 16);
        H.w = (unsigned int)eh[6] | ((unsigned int)eh[7] << 16);
        L.x = (unsigned int)el[0] | ((unsigned int)el[1] << 16);
        L.y = (unsigned int)el[2] | ((unsigned int)el[3] << 16);
        L.z = (unsigned int)el[4] | ((unsigned int)el[5] << 16);
        L.w = (unsigned int)el[6] | ((unsigned int)el[7] << 16);
        int base = t * 768 + (Nt * 3 + c) * 128;
        bfb[base + lane] = H;
        bfb[base + 64 + lane] = L;
    }

    float* tw = ws + WS_TW;
    for (int i = tid; i < 18; i += stp) tw[i] = ld_in(projw, i, bf);
    for (int i = tid; i < 6; i += stp) {
        float sc = ld_in(bng, i, bf) * rsqrtf(ld_in(bnv, i, bf) + 1e-5f);
        tw[18 + i] = sc;
        tw[24 + i] = ld_in(bnb, i, bf) - ld_in(bnm, i, bf) * sc;
    }
    for (int i = tid; i < 22;  i += stp) tw[32  + i] = ld_in(l0w, i, bf);
    for (int i = tid; i < 22;  i += stp) tw[54  + i] = ld_in(l0b, i, bf);
    for (int i = tid; i < 198; i += stp) tw[76  + i] = ld_in(lsw, i, bf);
    for (int i = tid; i < 22;  i += stp) tw[274 + i] = ld_in(lsb, i, bf);
    for (int i = tid; i < 242; i += stp) tw[296 + i] = ld_in(l1w, i, bf);
    for (int i = tid; i < 11;  i += stp) tw[538 + i] = ld_in(l1b, i, bf);
    for (int i = tid; i < 242; i += stp) tw[549 + i] = ld_in(l2w, i, bf);
    for (int i = tid; i < 11;  i += stp) tw[791 + i] = ld_in(l2b, i, bf);
    for (int i = tid; i < 36;  i += stp) tw[802 + i] = ld_in(sqw, i, bf);
    for (int i = tid; i < 2;   i += stp) tw[838 + i] = ld_in(sqb, i, bf);
    for (int i = tid; i < 33;  i += stp) tw[840 + i] = ld_in(lcw, i, bf);
    for (int i = tid; i < 3;   i += stp) tw[873 + i] = ld_in(lcb, i, bf);
}

// ---------------- fused MFMA conv + deformable sampling ----------------
__device__ inline float samp(const float* __restrict__ src, int y, int x) {
    bool valid = (y >= 0) & (y < HH) & (x >= 0) & (x < WW);
    int yc = min(max(y, 0), HH - 1);
    int xc = min(max(x, 0), WW - 1);
    float v = src[yc * WW + xc];
    return valid ? v : 0.0f;
}

// K-chunk c = dy; within chunk k=(g,j): ci=2g+(j>>2), dx=j&3 (dx==3 pad).
// C/D layout: col(channel)=lane&15, row(pixel)=(lane>>4)*4+reg (HW-verified).
__global__ __launch_bounds__(256) void dcn_fused(
        const void* __restrict__ guid, const int* __restrict__ flagp,
        const float* __restrict__ bias, const uint4* __restrict__ bfrag,
        const float* __restrict__ src, float* __restrict__ dst, int t) {
    __shared__ unsigned int hal[8][10][36];   // 11520 B
    __shared__ float outb[4][2][16][27];      // 13824 B
    const int bf = *flagp;
    const int bx = blockIdx.x % 38, by = blockIdx.x / 38;
    const int x0 = bx * 32, y0 = by * 8;
    const bool interior = (by >= 1) && (by <= 42) && (bx >= 1) && (bx <= 36);

    if (!bf) {
        const float* gp = (const float*)guid + (long long)(t * 8) * HWSZ;
        if (interior) {
            for (int idx = threadIdx.x; idx < 800; idx += 256) {
                int ci = idx / 100; int rem = idx % 100; int rr = rem / 10; int k = rem % 10;
                const float* rowp = gp + (long long)ci * HWSZ + (long long)(y0 - 1 + rr) * WW;
                const float4 v4 = *(const float4*)(rowp + (x0 - 4 + 4 * k));
                int c0 = 4 * k - 3;
                if (k == 0) {
                    hal[ci][rr][0] = bfsplit_pack(v4.w);
                } else if (k == 9) {
                    hal[ci][rr][33] = bfsplit_pack(v4.x);
                    hal[ci][rr][34] = bfsplit_pack(v4.y);
                    hal[ci][rr][35] = bfsplit_pack(v4.z);
                } else {
                    hal[ci][rr][c0 + 0] = bfsplit_pack(v4.x);
                    hal[ci][rr][c0 + 1] = bfsplit_pack(v4.y);
                    hal[ci][rr][c0 + 2] = bfsplit_pack(v4.z);
                    hal[ci][rr][c0 + 3] = bfsplit_pack(v4.w);
                }
            }
        } else {
            for (int idx = threadIdx.x; idx < 800; idx += 256) {
                int ci = idx / 100; int rem = idx % 100; int rr = rem / 10; int k = rem % 10;
                int gy = y0 - 1 + rr;
                int gxb = x0 - 4 + 4 * k;
                float vx = 0.f, vy = 0.f, vz = 0.f, vw = 0.f;
                if (gy >= 0 && gy < HH) {
                    const float* rowp = gp + (long long)ci * HWSZ + (long long)gy * WW;
                    if (gxb >= 0 && gxb + 3 < WW) {
                        const float4 v4 = *(const float4*)(rowp + gxb);
                        vx = v4.x; vy = v4.y; vz = v4.z; vw = v4.w;
                    } else {
                        if (gxb + 0 >= 0 && gxb + 0 < WW) vx = rowp[gxb + 0];
                        if (gxb + 1 >= 0 && gxb + 1 < WW) vy = rowp[gxb + 1];
                        if (gxb + 2 >= 0 && gxb + 2 < WW) vz = rowp[gxb + 2];
                        if (gxb + 3 >= 0 && gxb + 3 < WW) vw = rowp[gxb + 3];
                    }
                }
                int c0 = 4 * k - 3;
                if (c0 + 0 >= 0 && c0 + 0 < 36) hal[ci][rr][c0 + 0] = bfsplit_pack(vx);
                if (c0 + 1 >= 0 && c0 + 1 < 36) hal[ci][rr][c0 + 1] = bfsplit_pack(vy);
                if (c0 + 2 >= 0 && c0 + 2 < 36) hal[ci][rr][c0 + 2] = bfsplit_pack(vz);
                if (c0 + 3 >= 0 && c0 + 3 < 36) hal[ci][rr][c0 + 3] = bfsplit_pack(vw);
            }
        }
    } else {
        for (int idx = threadIdx.x; idx < 8 * 360; idx += 256) {
            int ci = idx / 360; int r = (idx % 360) / 36; int c = idx % 36;
            int gy = y0 - 1 + r, gx = x0 - 1 + c;
            float v = 0.f;
            if (c < 34 && gy >= 0 && gy < HH && gx >= 0 && gx < WW)
                v = ld_in(guid, (long long)(t * 8 + ci) * HWSZ + gy * WW + gx, bf);
            hal[ci][r][c] = bfsplit_pack(v);
        }
    }
    const int lane = threadIdx.x & 63;
    const int wave = threadIdx.x >> 6;
    const int col = lane & 15, g = lane >> 4;

    // B fragments: precomputed, coalesced dwordx4 loads
    FU Bh[2][3], Bl[2][3];
#pragma unroll
    for (int Nt = 0; Nt < 2; ++Nt)
#pragma unroll
    for (int c = 0; c < 3; ++c) {
        const uint4* bp = bfrag + (Nt * 3 + c) * 128;
        uint4 H = bp[lane];
        uint4 L = bp[64 + lane];
        Bh[Nt][c].u[0] = H.x; Bh[Nt][c].u[1] = H.y; Bh[Nt][c].u[2] = H.z; Bh[Nt][c].u[3] = H.w;
        Bl[Nt][c].u[0] = L.x; Bl[Nt][c].u[1] = L.y; Bl[Nt][c].u[2] = L.z; Bl[Nt][c].u[3] = L.w;
    }
    __syncthreads();

#pragma unroll
    for (int m = 0; m < 4; ++m) {
        const int M = wave * 4 + m;
        const int py = M >> 1;
        const int xoff = (M & 1) * 16;
        const int pxx = xoff + col;
        FU Ah[3], Al[3];
#pragma unroll
        for (int c = 0; c < 3; ++c) {
            const unsigned int* r0 = &hal[2 * g][py + c][pxx];
            const unsigned int* r1 = &hal[2 * g + 1][py + c][pxx];
            unsigned int q0 = r0[0], q1 = r0[1], q2 = r0[2], q3 = r0[3];
            unsigned int q4 = r1[0], q5 = r1[1], q6 = r1[2], q7 = r1[3];
            Ah[c].u[0] = __builtin_amdgcn_perm(q1, q0, 0x05040100u);
            Ah[c].u[1] = __builtin_amdgcn_perm(q3, q2, 0x05040100u);
            Ah[c].u[2] = __builtin_amdgcn_perm(q5, q4, 0x05040100u);
            Ah[c].u[3] = __builtin_amdgcn_perm(q7, q6, 0x05040100u);
            Al[c].u[0] = __builtin_amdgcn_perm(q1, q0, 0x07060302u);
            Al[c].u[1] = __builtin_amdgcn_perm(q3, q2, 0x07060302u);
            Al[c].u[2] = __builtin_amdgcn_perm(q5, q4, 0x07060302u);
            Al[c].u[3] = __builtin_amdgcn_perm(q7, q6, 0x07060302u);
        }
#pragma unroll
        for (int Nt = 0; Nt < 2; ++Nt) {
            f32x4 acc = {0.f, 0.f, 0.f, 0.f};
#pragma unroll
            for (int c = 0; c < 3; ++c) {
                acc = __builtin_amdgcn_mfma_f32_16x16x32_bf16(Ah[c].v, Bh[Nt][c].v, acc, 0, 0, 0);
                acc = __builtin_amdgcn_mfma_f32_16x16x32_bf16(Al[c].v, Bh[Nt][c].v, acc, 0, 0, 0);
                acc = __builtin_amdgcn_mfma_f32_16x16x32_bf16(Ah[c].v, Bl[Nt][c].v, acc, 0, 0, 0);
            }
            const int co = Nt * 16 + col;
            if (co < 25) {
                float bs = bias[co];
#pragma unroll
                for (int r = 0; r < 4; ++r)
                    outb[wave][m & 1][g * 4 + r][co] = acc[r] + bs;
            }
        }
        // per-m finalize: 16 pixels, 4 lanes each (quad q=g), taps tap=i*4+q
        {
            const int px = col;
            const int gy = y0 + py;
            const int gx = x0 + xoff + px;
            const float* ob = &outb[wave][m & 1][px][0];
            float sg[3], oyv[3], oxv[3];
            float psum = 0.f;
#pragma unroll
            for (int i = 0; i < 3; ++i) {
                int tap = i * 4 + g;
                bool valid = tap < 9;
                int tc = valid ? tap : 8;
                float wv = ob[tc];
                float sgv = 1.f / (1.f + __expf(-wv));
                sg[i] = valid ? sgv : 0.f;
                psum += sg[i];
                int kp = (tap < 4) ? tap : tap - 1;
                kp = min(kp, 7);
                float oy = ob[9 + 2 * kp];
                float ox = ob[10 + 2 * kp];
                bool use_off = valid && (tap != 4);
                oyv[i] = use_off ? oy : 0.f;
                oxv[i] = use_off ? ox : 0.f;
            }
            psum += __shfl_xor(psum, 16);
            psum += __shfl_xor(psum, 32);
            const float inv = 1.f / (psum + 1e-8f);
            float out = 0.f;
#pragma unroll
            for (int i = 0; i < 3; ++i) {
                int tap = min(i * 4 + g, 8);
                float w = sg[i] * inv;
                int d3 = tap / 3;
                int dy = d3 - 1, dx = tap - 3 * d3 - 1;
                float ys = (float)(gy + dy) + oyv[i];
                float xs = (float)(gx + dx) + oxv[i];
                float yf = floorf(ys), xf = floorf(xs);
                float wy = ys - yf, wx = xs - xf;
                int yi = (int)yf, xi = (int)xf;
                float v00 = samp(src, yi, xi);
                float v01 = samp(src, yi, xi + 1);
                float v10 = samp(src, yi + 1, xi);
                float v11 = samp(src, yi + 1, xi + 1);
                float sv = v00 * (1.f - wy) * (1.f - wx) + v01 * (1.f - wy) * wx
                         + v10 * wy * (1.f - wx) + v11 * wy * wx;
                out = fmaf(w, sv, out);
            }
            out += __shfl_xor(out, 16);
            out += __shfl_xor(out, 32);
            if (g == 0) dst[gy * WW + gx] = out;
        }
    }
}

// ---------------- tail2m: fused tail1+tail2 (one-shot vectorized staging) ----------------
__global__ __launch_bounds__(256) void tail2m(
        const void* __restrict__ attn, const int* __restrict__ flagp,
        const float* __restrict__ tw, const float* __restrict__ feats,
        float* __restrict__ a11, float* __restrict__ a21, float* __restrict__ agg) {
    __shared__ float a1t[22][10][36];
    __shared__ float ft[3][10][36];
    const int bf = *flagp;
    const int bx = blockIdx.x % 38, by = blockIdx.x / 38;
    const int x0 = bx * 32, y0 = by * 8;
    const bool interior = (by >= 1) && (by <= 42) && (bx >= 1) && (bx <= 36);

    if (!bf && interior) {
        for (int idx = threadIdx.x; idx < 1900; idx += 256) {
            int plane = idx / 100; int rem = idx % 100; int rr = rem / 10; int k = rem % 10;
            const float* rowp;
            float sc, bc;
            if (plane < 16) {
                rowp = (const float*)attn + (long long)plane * HWSZ + (long long)(y0 - 1 + rr) * WW;
                sc = tw[32 + plane]; bc = tw[54 + plane];
            } else {
                rowp = feats + (long long)(3 + plane - 16) * HWSZ + (long long)(y0 - 1 + rr) * WW;
                sc = 1.f; bc = 0.f;
            }
            const float4 v4 = *(const float4*)(rowp + (x0 - 4 + 4 * k));
            float t0 = fmaf(v4.x, sc, bc), t1 = fmaf(v4.y, sc, bc);
            float t2 = fmaf(v4.z, sc, bc), t3 = fmaf(v4.w, sc, bc);
            float* drow = (plane < 16) ? &a1t[plane][rr][0] : &ft[plane - 16][rr][0];
            int c0 = 4 * k - 3;
            if (k == 0) {
                drow[0] = t3;
            } else if (k == 9) {
                drow[33] = t0; drow[34] = t1; drow[35] = t2;
            } else {
                drow[c0 + 0] = t0; drow[c0 + 1] = t1; drow[c0 + 2] = t2; drow[c0 + 3] = t3;
            }
        }
    } else {
        for (int idx = threadIdx.x; idx < 19 * 360; idx += 256) {
            int plane = idx / 360; int rem = idx % 360; int rr = rem / 36; int c = rem % 36;
            int gy = y0 - 1 + rr, gx = x0 - 1 + c;
            bool ok = (c < 34) && gy >= 0 && gy < HH && gx >= 0 && gx < WW;
            if (plane < 16) {
                float v = 0.f;
                if (ok) v = fmaf(ld_in(attn, (long long)plane * HWSZ + gy * WW + gx, bf),
                                 tw[32 + plane], tw[54 + plane]);
                a1t[plane][rr][c] = v;
            } else {
                ft[plane - 16][rr][c] = ok ? feats[(long long)(3 + plane - 16) * HWSZ + gy * WW + gx] : 0.f;
            }
        }
    }
    __syncthreads();
    // sf planes -> a1t[16..21]
    for (int idx = threadIdx.x; idx < 6 * 340; idx += 256) {
        int j = idx / 340; int r = (idx % 340) / 34; int cc = idx % 34;
        int gy = y0 - 1 + r, gx = x0 - 1 + cc;
        bool ok = (gy >= 0 && gy < HH && gx >= 0 && gx < WW);
        float o = 0.f;
        if (ok) {
            float f0 = ft[0][r][cc], f1 = ft[1][r][cc], f2 = ft[2][r][cc];
            float v = tw[j * 3 + 0] * f0 + tw[j * 3 + 1] * f1 + tw[j * 3 + 2] * f2;
            v = v * tw[18 + j] + tw[24 + j];
            v = (v >= 0.f) ? v : 0.2f * v;
            o = fmaf(v, tw[32 + 16 + j], tw[54 + 16 + j]);
        }
        a1t[16 + j][r][cc] = o;
    }
    __syncthreads();
    const int lx = threadIdx.x & 31, ly = threadIdx.x >> 5;
    float acc1[11], acc2[11];
#pragma unroll
    for (int j = 0; j < 11; ++j) { acc1[j] = tw[538 + j]; acc2[j] = tw[791 + j]; }
    for (int c = 0; c < 22; ++c) {
        float a1c = a1t[c][ly + 1][lx + 1];
        float a2c = tw[274 + c];
#pragma unroll
        for (int dy = 0; dy < 3; ++dy)
#pragma unroll
        for (int dx = 0; dx < 3; ++dx)
            a2c = fmaf(a1t[c][ly + dy][lx + dx], tw[76 + c * 9 + dy * 3 + dx], a2c);
#pragma unroll
        for (int j = 0; j < 11; ++j) {
            acc1[j] = fmaf(a1c, tw[296 + j * 22 + c], acc1[j]);
            acc2[j] = fmaf(a2c, tw[549 + j * 22 + c], acc2[j]);
        }
    }
    const int p = (y0 + ly) * WW + x0 + lx;
    float s = 0.0f, mx = -1e30f;
#pragma unroll
    for (int j = 0; j < 11; ++j) {
        a11[j * HWSZ + p] = acc1[j];
        a21[j * HWSZ + p] = acc2[j];
        s += acc1[j] + acc2[j];
        mx = fmaxf(mx, fmaxf(acc1[j], acc2[j]));
    }
    agg[p] = s * (1.0f / 22.0f);
    agg[HWSZ + p] = mx;
}

// ---------------- tail3 (unchanged, known-good) ----------------
__global__ __launch_bounds__(256) void tail3(
        const int* __restrict__ flagp, const float* __restrict__ tw,
        const float* __restrict__ feats,
        const float* __restrict__ a11, const float* __restrict__ a21,
        const float* __restrict__ agg, void* __restrict__ out) {
    __shared__ float t0[10][34], t1[10][34];
    const int bx = blockIdx.x % 38, by = blockIdx.x / 38;
    const int x0 = bx * 32, y0 = by * 8;
    for (int idx = threadIdx.x; idx < 340; idx += 256) {
        int r = idx / 34, cc = idx % 34;
        int gy = y0 - 1 + r, gx = x0 - 1 + cc;
        bool ok = (gy >= 0 && gy < HH && gx >= 0 && gx < WW);
        t0[r][cc] = ok ? agg[gy * WW + gx] : 0.0f;
        t1[r][cc] = ok ? agg[HWSZ + gy * WW + gx] : 0.0f;
    }
    __syncthreads();
    const int lx = threadIdx.x % 32, ly = threadIdx.x / 32;
    float s0 = tw[838], s1 = tw[839];
#pragma unroll
    for (int dy = 0; dy < 3; ++dy)
#pragma unroll
        for (int dx = 0; dx < 3; ++dx) {
            float v0 = t0[ly + dy][lx + dx], v1 = t1[ly + dy][lx + dx];
            s0 = fmaf(v0, tw[802 + 0 * 18 + 0 * 9 + dy * 3 + dx], s0);
            s0 = fmaf(v1, tw[802 + 0 * 18 + 1 * 9 + dy * 3 + dx], s0);
            s1 = fmaf(v0, tw[802 + 1 * 18 + 0 * 9 + dy * 3 + dx], s1);
            s1 = fmaf(v1, tw[802 + 1 * 18 + 1 * 9 + dy * 3 + dx], s1);
        }
    float sg0 = 1.0f / (1.0f + __expf(-s0));
    float sg1 = 1.0f / (1.0f + __expf(-s1));
    const int p = (y0 + ly) * WW + x0 + lx;
    float at3[3] = { tw[873], tw[874], tw[875] };
#pragma unroll
    for (int j = 0; j < 11; ++j) {
        float at = a11[j * HWSZ + p] * sg0 + a21[j * HWSZ + p] * sg1;
#pragma unroll
        for (int i = 0; i < 3; ++i) at3[i] = fmaf(at, tw[840 + i * 11 + j], at3[i]);
    }
    float o = feats[3 * HWSZ + p] * at3[0] + feats[4 * HWSZ + p] * at3[1]
            + feats[5 * HWSZ + p] * at3[2];
    int bf = *flagp;
    if (bf) ((__hip_bfloat16*)out)[p] = __float2bfloat16(o);
    else    ((float*)out)[p] = o;
}

// ---------------- host ----------------
extern "C" void kernel_launch(void* const* d_in, const int* in_sizes, int n_in,
                              void* d_out, int out_size, void* d_ws, size_t ws_size,
                              hipStream_t stream) {
    (void)in_sizes; (void)n_in; (void)out_size; (void)ws_size;
    float* WSF = (float*)d_ws;
    const int* flagp = (const int*)d_ws;
    float* cw   = WSF + WS_CW;
    float* tw   = WSF + WS_TW;
    const uint4* bfb = (const uint4*)(WSF + WS_BF);
    float* FB   = WSF + WS_FB;             // 7 planes
    float* A11  = FB + 7 * HWSZ;           // 11 planes
    float* A21  = A11 + 11 * HWSZ;         // 11 planes
    float* AGG  = A21 + 11 * HWSZ;         // 2 planes

    prep_all<<<1672, 256, 0, stream>>>(d_in[0], d_in[1],
        d_in[4], d_in[5], d_in[6], d_in[7],
        d_in[8], d_in[9], d_in[10], d_in[11], d_in[12],
        d_in[13], d_in[14], d_in[15], d_in[16],
        d_in[17], d_in[18], d_in[19], d_in[20],
        d_in[21], d_in[22], d_in[23], d_in[24], WSF);

    for (int t = 0; t < 6; ++t) {
        const float* src = (t == 0) ? (FB + 6 * HWSZ) : (FB + (t - 1) * HWSZ);
        dcn_fused<<<44 * 38, 256, 0, stream>>>(d_in[1], flagp, cw + t * 32,
                                               bfb + t * 768, src, FB + t * HWSZ, t);
    }
    tail2m<<<44 * 38, 256, 0, stream>>>(d_in[2], flagp, tw, FB, A11, A21, AGG);
    tail3<<<44 * 38, 256, 0, stream>>>(flagp, tw, FB, A11, A21, AGG, d_out);
}